// Round 14
// baseline (226.572 us; speedup 1.0000x reference)
//
#include <hip/hip_runtime.h>
#include <math.h>

// SplineConv x2 (K=4, dim=1, degree=1, mean aggr) + ELU + log_softmax.
// R20: R19 (xw1 4 nodes/thread) confirmed the lever: 231.2 -> 225.6us.
// Extend the same validated lever one notch: xw1 part = 8 NODES PER
// THREAD (48 nodes/block, 1042 blocks, same 256t/40-colgroup geometry).
// 48 ds_read_b128/thread amortize over 8 nodes (188MB total LDS reads);
// W-staging halves again. ~32 extra acc VGPR (est ~90-100, >=3 waves).
// Everything else bit-for-bit R19. Pre-commit: gain < 3us -> ROOFLINE.

#define F_IN   48
#define HID    32
#define NCLS   10
#define KS     4
#define BKT_SH 8               // 256 nodes per bucket
#define TILE   4096            // edges per bucket_scatter block

__device__ inline unsigned short f2bf(float f) {
    unsigned x = __float_as_uint(f);
    unsigned r = x + 0x7FFFu + ((x >> 16) & 1u);  // RNE
    return (unsigned short)(r >> 16);
}
__device__ inline float bf2f(unsigned short u) {
    return __uint_as_float(((unsigned)u) << 16);
}

// ---------- CSR build (bucketed two-level sort) ----------

__global__ void bucket_hist_kernel(const int* __restrict__ ei, int* __restrict__ bcnt,
                                   int E, int NB) {
    __shared__ int lcnt[256];
    int t = threadIdx.x;
    lcnt[t] = 0;
    __syncthreads();
    int e0 = blockIdx.x * TILE;
    int n = min(TILE, E - e0);
    for (int r = 0; r < TILE / 256; ++r) {
        int i = r * 256 + t;
        if (i < n) atomicAdd(&lcnt[ei[E + e0 + i] >> BKT_SH], 1);
    }
    __syncthreads();
    if (t < NB && lcnt[t] > 0) atomicAdd(&bcnt[t], lcnt[t]);
}

__global__ void mini_scan_kernel(const int* __restrict__ bcnt, int* __restrict__ bbase,
                                 int* __restrict__ gcur, int NB) {
    __shared__ int a[256], c[256];
    int t = threadIdx.x;
    int v = (t < NB) ? bcnt[t] : 0;
    a[t] = v; c[t] = v;
    __syncthreads();
    for (int o = 1; o < 256; o <<= 1) {
        int w = (t >= o) ? a[t - o] : 0;
        __syncthreads();
        a[t] += w;
        __syncthreads();
    }
    int ex = a[t] - c[t];
    if (t < NB) { bbase[t] = ex; gcur[t] = ex; }
    if (t == 0) bbase[NB] = a[255];
}

__global__ void bucket_scatter_kernel(const int* __restrict__ ei, const float* __restrict__ ea,
                                      int* __restrict__ gcur, uint2* __restrict__ tpd,
                                      int E, int NB) {
    __shared__ unsigned spl[TILE];
    __shared__ unsigned short sdst[TILE];
    __shared__ unsigned short inv[TILE];
    __shared__ int lcnt[256], loff[256], lrank[256], gb[256];
    int t = threadIdx.x;
    lcnt[t] = 0; lrank[t] = 0;
    __syncthreads();
    int e0 = blockIdx.x * TILE;
    int n = min(TILE, E - e0);
    for (int r = 0; r < TILE / 256; ++r) {
        int i = r * 256 + t;
        if (i < n) {
            int e = e0 + i;
            int src = ei[e];
            int dst = ei[E + e];
            float u = ea[e];
            float v = u * (float)(KS - 1);
            float vf = floorf(v);
            int k0 = min(max((int)vf, 0), KS - 1);
            unsigned qf = (unsigned)((v - vf) * 16383.f + 0.5f);  // 14-bit frac
            spl[i] = (unsigned)src | ((unsigned)k0 << 16) | (qf << 18);
            sdst[i] = (unsigned short)dst;
            atomicAdd(&lcnt[dst >> BKT_SH], 1);
        }
    }
    __syncthreads();
    loff[t] = lcnt[t];
    __syncthreads();
    for (int o = 1; o < 256; o <<= 1) {
        int w = (t >= o) ? loff[t - o] : 0;
        __syncthreads();
        loff[t] += w;
        __syncthreads();
    }
    int ex = loff[t] - lcnt[t];
    __syncthreads();
    loff[t] = ex;
    if (t < NB) gb[t] = atomicAdd(&gcur[t], lcnt[t]);
    __syncthreads();
    for (int r = 0; r < TILE / 256; ++r) {
        int i = r * 256 + t;
        if (i < n) {
            int b = sdst[i] >> BKT_SH;
            int p = loff[b] + atomicAdd(&lrank[b], 1);
            inv[p] = (unsigned short)i;
        }
    }
    __syncthreads();
    for (int r = 0; r < TILE / 256; ++r) {
        int j = r * 256 + t;
        if (j < n) {
            int i = inv[j];
            int d = sdst[i];
            int b = d >> BKT_SH;
            int pos = gb[b] + (j - loff[b]);
            tpd[pos] = make_uint2(spl[i], (unsigned)d);
        }
    }
}

// ---------- fused node_sort + xw1 (heterogeneous blocks) ----------
// Blocks [0,NB): per-bucket node sort (tpd -> spk, offs).
// Blocks [NB, NB+XB): xw1 table build, 256 threads = 40 colgroups x 6
// groups x 8 nodes (48 nodes/block). Each thread's 48 ds_read_b128 of W
// serve EIGHT nodes; x loaded 8 float4 per fb-step.

__global__ __launch_bounds__(256) void nsort_xw1_kernel(
        const uint2* __restrict__ tpd, const int* __restrict__ bbase,
        unsigned* __restrict__ spk, int* __restrict__ offs, int N, int NB,
        const float* __restrict__ X, const float* __restrict__ W,
        const float* __restrict__ R, unsigned short* __restrict__ outk,
        float* __restrict__ outr) {
    __shared__ union {
        struct { int hc[256]; int hs[256]; int hr[256]; } ns;
        float lw[48 * 160];
    } sm;
    int t = threadIdx.x;
    if ((int)blockIdx.x < NB) {
        // ---- node_sort part (unchanged from R19) ----
        int b = blockIdx.x;
        int nb0 = b << BKT_SH;
        int nb = min(256, N - nb0);
        int base = bbase[b];
        int m = bbase[b + 1] - base;
        sm.ns.hc[t] = 0; sm.ns.hr[t] = 0;
        __syncthreads();
        for (int i = t; i < m; i += 256) atomicAdd(&sm.ns.hc[tpd[base + i].y - nb0], 1);
        __syncthreads();
        sm.ns.hs[t] = sm.ns.hc[t];
        __syncthreads();
        for (int o = 1; o < 256; o <<= 1) {
            int w = (t >= o) ? sm.ns.hs[t - o] : 0;
            __syncthreads();
            sm.ns.hs[t] += w;
            __syncthreads();
        }
        if (t < nb) offs[nb0 + t] = base + (sm.ns.hs[t] - sm.ns.hc[t]);
        if (b == NB - 1 && t == 0) offs[N] = base + m;
        for (int i = t; i < m; i += 256) {
            uint2 rec = tpd[base + i];
            int d = rec.y - nb0;
            int p = (sm.ns.hs[d] - sm.ns.hc[d]) + atomicAdd(&sm.ns.hr[d], 1);
            spk[base + p] = rec.x;
        }
        return;
    }
    // ---- xw1 part: 8 nodes per thread ----
    int bx = blockIdx.x - NB;
    for (int i = t; i < 48 * 160; i += 256) {
        int f = i / 160;
        int col = i - f * 160;
        sm.lw[i] = (col < 128) ? W[(size_t)(col >> 5) * (48 * 32) + f * 32 + (col & 31)]
                               : R[f * 32 + (col - 128)];
    }
    __syncthreads();
    int g = t % 40;      // colgroup (4 cols)
    int lp = t / 40;     // node group 0..5 (lp 6 = idle tail threads)
    if (lp >= 6) return;
    int nbase = bx * 48 + lp * 8;   // 8 nodes per thread
    if (nbase >= N) return;
    int mm[8];
#pragma unroll
    for (int k = 0; k < 8; ++k) mm[k] = min(nbase + k, N - 1);
    const float4* X4 = (const float4*)X;       // row stride 12 float4
    const float4* lw4 = (const float4*)sm.lw;  // lw4[f*40 + g]
    float4 a[8];
#pragma unroll
    for (int k = 0; k < 8; ++k) a[k] = make_float4(0.f, 0.f, 0.f, 0.f);
    for (int fb = 0; fb < 12; ++fb) {
        float4 v[8];
#pragma unroll
        for (int k = 0; k < 8; ++k) v[k] = X4[(size_t)mm[k] * 12 + fb];
#pragma unroll
        for (int j = 0; j < 4; ++j) {
            float4 w = lw4[(fb * 4 + j) * 40 + g];
#pragma unroll
            for (int k = 0; k < 8; ++k) {
                float s = (j == 0) ? v[k].x : (j == 1) ? v[k].y
                         : (j == 2) ? v[k].z : v[k].w;
                a[k].x = fmaf(s, w.x, a[k].x);
                a[k].y = fmaf(s, w.y, a[k].y);
                a[k].z = fmaf(s, w.z, a[k].z);
                a[k].w = fmaf(s, w.w, a[k].w);
            }
        }
    }
    int nv = min(N - nbase, 8);  // number of valid nodes
    if (g < 32) {
#pragma unroll
        for (int k = 0; k < 8; ++k) {
            if (k < nv) {
                uint2 u;
                u.x = f2bf(a[k].x) | ((unsigned)f2bf(a[k].y) << 16);
                u.y = f2bf(a[k].z) | ((unsigned)f2bf(a[k].w) << 16);
                *(uint2*)(outk + (size_t)(nbase + k) * (KS * HID) + g * 4) = u;
            }
        }
    } else {
        int o = 4 * g - 128;
#pragma unroll
        for (int k = 0; k < 8; ++k) {
            if (k < nv) *(float4*)(outr + (size_t)(nbase + k) * HID + o) = a[k];
        }
    }
}

__global__ void xw2_kernel(const float* __restrict__ H, const float* __restrict__ W,
                           const float* __restrict__ R, unsigned short* __restrict__ outk,
                           float* __restrict__ outr, int n) {
    __shared__ float lw2[32 * 50];
    int t = threadIdx.x;
    for (int i = t; i < 32 * 50; i += 256) {
        int f = i / 50;
        int col = i - f * 50;
        lw2[i] = (col < 40) ? W[(size_t)(col / 10) * (32 * 10) + f * 10 + (col % 10)]
                            : R[f * 10 + (col - 40)];
    }
    __syncthreads();
    int total = (n / 2) * 25;
    int id = blockIdx.x * blockDim.x + t;
    if (id >= total) return;
    int p = id % 25;
    int pr = id / 25;
    int n0 = 2 * pr;
    const float4* H0 = (const float4*)(H + (size_t)n0 * HID);
    const float4* H1 = (const float4*)(H + (size_t)(n0 + 1) * HID);
    float4 h0[8], h1[8];
#pragma unroll
    for (int i = 0; i < 8; ++i) { h0[i] = H0[i]; h1[i] = H1[i]; }
    const float2* lwp = (const float2*)lw2;  // lwp[f*25 + p]
    float ax0 = 0.f, ay0 = 0.f, ax1 = 0.f, ay1 = 0.f;
#pragma unroll
    for (int fb = 0; fb < 8; ++fb) {
        float4 v0 = h0[fb], v1 = h1[fb];
#pragma unroll
        for (int j = 0; j < 4; ++j) {
            float s0 = (j == 0) ? v0.x : (j == 1) ? v0.y : (j == 2) ? v0.z : v0.w;
            float s1 = (j == 0) ? v1.x : (j == 1) ? v1.y : (j == 2) ? v1.z : v1.w;
            float2 w = lwp[(fb * 4 + j) * 25 + p];
            ax0 = fmaf(s0, w.x, ax0); ay0 = fmaf(s0, w.y, ay0);
            ax1 = fmaf(s1, w.x, ax1); ay1 = fmaf(s1, w.y, ay1);
        }
    }
    int col = 2 * p;
    if (col < KS * NCLS) {
        *(unsigned*)(outk + (size_t)n0 * (KS * NCLS) + col) =
            f2bf(ax0) | ((unsigned)f2bf(ay0) << 16);
        *(unsigned*)(outk + (size_t)(n0 + 1) * (KS * NCLS) + col) =
            f2bf(ax1) | ((unsigned)f2bf(ay1) << 16);
    } else {
        int o = col - KS * NCLS;
        *(float2*)(outr + (size_t)n0 * NCLS + o) = make_float2(ax0, ay0);
        *(float2*)(outr + (size_t)(n0 + 1) * NCLS + o) = make_float2(ax1, ay1);
    }
}

// ---------- aggregation ----------

// Decode a packed spline record into a row pointer, k1-k0 offset, frac.
#define DECODE32(p, row, dk, fr)                                          \
    {   int src_ = (p) & 0xFFFF;                                          \
        int k0_ = ((p) >> 16) & 3;                                        \
        int k1_ = min(k0_ + 1, KS - 1);                                   \
        fr = (float)((p) >> 18) * (1.f / 16383.f);                        \
        row = xwk + (size_t)src_ * (KS * HID) + k0_ * HID + cg * 4;       \
        dk = (k1_ - k0_) * HID; }

__device__ inline void fma4(uint2 v0, uint2 v1, float fr, float4& a) {
    float w0 = 1.f - fr;
    a.x = fmaf(w0, __uint_as_float(v0.x << 16), a.x);
    a.x = fmaf(fr, __uint_as_float(v1.x << 16), a.x);
    a.y = fmaf(w0, __uint_as_float(v0.x & 0xFFFF0000u), a.y);
    a.y = fmaf(fr, __uint_as_float(v1.x & 0xFFFF0000u), a.y);
    a.z = fmaf(w0, __uint_as_float(v0.y << 16), a.z);
    a.z = fmaf(fr, __uint_as_float(v1.y << 16), a.z);
    a.w = fmaf(w0, __uint_as_float(v0.y & 0xFFFF0000u), a.w);
    a.w = fmaf(fr, __uint_as_float(v1.y & 0xFFFF0000u), a.w);
}

// agg1: one wave per node; lane = (slot 0..7, chgroup 0..7). Quad-unrolled:
// 32 edges (64 row-gathers) in flight per wave.
__global__ void agg1_kernel(const unsigned short* __restrict__ xwk,
                            const float* __restrict__ xroot,
                            const int* __restrict__ offs, const unsigned* __restrict__ spk,
                            const float* __restrict__ bias, float* __restrict__ h, int n) {
    int lane = threadIdx.x & 63;
    int cg = lane & 7;       // channels 4cg..4cg+3
    int slot = lane >> 3;    // 8 edge slots
    int node = blockIdx.x * 4 + (threadIdx.x >> 6);
    if (node >= n) return;
    int beg = offs[node];
    int end = offs[node + 1];
    float4 a0 = {0, 0, 0, 0}, a1 = {0, 0, 0, 0};
    int e = beg + slot;
    while (e + 24 < end) {
        unsigned p0 = spk[e], p1 = spk[e + 8], p2 = spk[e + 16], p3 = spk[e + 24];
        const unsigned short *r0, *r1, *r2, *r3;
        int d0, d1, d2, d3;
        float f0, f1, f2, f3;
        DECODE32(p0, r0, d0, f0);
        DECODE32(p1, r1, d1, f1);
        DECODE32(p2, r2, d2, f2);
        DECODE32(p3, r3, d3, f3);
        uint2 v00 = *(const uint2*)r0, v01 = *(const uint2*)(r0 + d0);
        uint2 v10 = *(const uint2*)r1, v11 = *(const uint2*)(r1 + d1);
        uint2 v20 = *(const uint2*)r2, v21 = *(const uint2*)(r2 + d2);
        uint2 v30 = *(const uint2*)r3, v31 = *(const uint2*)(r3 + d3);
        fma4(v00, v01, f0, a0);
        fma4(v10, v11, f1, a1);
        fma4(v20, v21, f2, a0);
        fma4(v30, v31, f3, a1);
        e += 32;
    }
    while (e < end) {
        unsigned p = spk[e];
        const unsigned short* r;
        int d;
        float f;
        DECODE32(p, r, d, f);
        uint2 v0 = *(const uint2*)r, v1 = *(const uint2*)(r + d);
        fma4(v0, v1, f, a0);
        e += 8;
    }
    float4 s;
    s.x = a0.x + a1.x; s.y = a0.y + a1.y; s.z = a0.z + a1.z; s.w = a0.w + a1.w;
#pragma unroll
    for (int m = 8; m < 64; m <<= 1) {   // reduce across 8 slots
        s.x += __shfl_xor(s.x, m, 64);
        s.y += __shfl_xor(s.y, m, 64);
        s.z += __shfl_xor(s.z, m, 64);
        s.w += __shfl_xor(s.w, m, 64);
    }
    if (slot == 0) {
        int deg = end - beg;
        float inv = 1.f / (float)(deg > 0 ? deg : 1);
        float4 r = *(const float4*)(xroot + (size_t)node * HID + cg * 4);
        float4 b = *(const float4*)(bias + cg * 4);
        float4 o;
        o.x = fmaf(s.x, inv, r.x + b.x);
        o.y = fmaf(s.y, inv, r.y + b.y);
        o.z = fmaf(s.z, inv, r.z + b.z);
        o.w = fmaf(s.w, inv, r.w + b.w);
        o.x = (o.x > 0.f) ? o.x : expm1f(o.x);
        o.y = (o.y > 0.f) ? o.y : expm1f(o.y);
        o.z = (o.z > 0.f) ? o.z : expm1f(o.z);
        o.w = (o.w > 0.f) ? o.w : expm1f(o.w);
        *(float4*)(h + (size_t)node * HID + cg * 4) = o;
    }
}

// agg2: one wave per node; lane = (slot 0..7, pair 0..7; pairs 0..4 active).
// dword loads = 2 bf16 channels; quad-unrolled -> 32 edges in flight.
__global__ void agg2_kernel(const unsigned short* __restrict__ xwk,
                            const float* __restrict__ xroot,
                            const int* __restrict__ offs, const unsigned* __restrict__ spk,
                            const float* __restrict__ bias, float* __restrict__ out, int n) {
    int lane = threadIdx.x & 63;
    int u = lane & 7;        // channel pair (2u, 2u+1); valid u<5
    int slot = lane >> 3;    // 8 edge slots
    int node = blockIdx.x * 4 + (threadIdx.x >> 6);
    bool nv = node < n;
    if (!nv) node = n - 1;
    int up = min(u, 4);
    int beg = offs[node];
    int end = offs[node + 1];
    float a0l = 0.f, a0h = 0.f, a1l = 0.f, a1h = 0.f;

#define DEC2(p, q0, q1, fr)                                               \
    {   int src_ = (p) & 0xFFFF;                                          \
        int k0_ = ((p) >> 16) & 3;                                        \
        int k1_ = min(k0_ + 1, KS - 1);                                   \
        fr = (float)((p) >> 18) * (1.f / 16383.f);                        \
        const unsigned short* row_ = xwk + (size_t)src_ * 40;             \
        q0 = (const unsigned*)(row_ + k0_ * 10) + up;                     \
        q1 = (const unsigned*)(row_ + k1_ * 10) + up; }

#define FMA2(t0, t1, fr, al, ah)                                          \
    {   float w0_ = 1.f - fr;                                             \
        al = fmaf(w0_, __uint_as_float((t0) << 16), al);                  \
        al = fmaf(fr,  __uint_as_float((t1) << 16), al);                  \
        ah = fmaf(w0_, __uint_as_float((t0) & 0xFFFF0000u), ah);          \
        ah = fmaf(fr,  __uint_as_float((t1) & 0xFFFF0000u), ah); }

    int e = beg + slot;
    while (e + 24 < end) {
        unsigned p0 = spk[e], p1 = spk[e + 8], p2 = spk[e + 16], p3 = spk[e + 24];
        const unsigned *q00, *q01, *q10, *q11, *q20, *q21, *q30, *q31;
        float f0, f1, f2, f3;
        DEC2(p0, q00, q01, f0);
        DEC2(p1, q10, q11, f1);
        DEC2(p2, q20, q21, f2);
        DEC2(p3, q30, q31, f3);
        unsigned t00 = *q00, t01 = *q01;
        unsigned t10 = *q10, t11 = *q11;
        unsigned t20 = *q20, t21 = *q21;
        unsigned t30 = *q30, t31 = *q31;
        FMA2(t00, t01, f0, a0l, a0h);
        FMA2(t10, t11, f1, a1l, a1h);
        FMA2(t20, t21, f2, a0l, a0h);
        FMA2(t30, t31, f3, a1l, a1h);
        e += 32;
    }
    while (e < end) {
        unsigned p = spk[e];
        const unsigned *q0, *q1;
        float f;
        DEC2(p, q0, q1, f);
        unsigned t0 = *q0, t1 = *q1;
        FMA2(t0, t1, f, a0l, a0h);
        e += 8;
    }
    float vl = a0l + a1l, vh = a0h + a1h;
    if (u > 4) { vl = 0.f; vh = 0.f; }
#pragma unroll
    for (int m = 8; m < 64; m <<= 1) {   // reduce across 8 slots
        vl += __shfl_xor(vl, m, 64);
        vh += __shfl_xor(vh, m, 64);
    }
    int deg = end - beg;
    float invd = 1.f / (float)(deg > 0 ? deg : 1);
    float l0 = -INFINITY, l1 = -INFINITY;
    if (u < 5) {
        float2 xr = *(const float2*)(xroot + (size_t)node * NCLS + 2 * u);
        l0 = fmaf(vl, invd, xr.x + bias[2 * u]);
        l1 = fmaf(vh, invd, xr.y + bias[2 * u + 1]);
    }
    float mx = fmaxf(l0, l1);
#pragma unroll
    for (int m = 1; m < 8; m <<= 1) mx = fmaxf(mx, __shfl_xor(mx, m, 64));
    float sden = (u < 5) ? (expf(l0 - mx) + expf(l1 - mx)) : 0.f;
#pragma unroll
    for (int m = 1; m < 8; m <<= 1) sden += __shfl_xor(sden, m, 64);
    if (nv && slot == 0 && u < 5) {
        float ls = logf(sden);
        *(float2*)(out + (size_t)node * NCLS + 2 * u) =
            make_float2(l0 - mx - ls, l1 - mx - ls);
    }
}

extern "C" void kernel_launch(void* const* d_in, const int* in_sizes, int n_in,
                              void* d_out, int out_size, void* d_ws, size_t ws_size,
                              hipStream_t stream) {
    const float* x       = (const float*)d_in[0];
    const int*   ei      = (const int*)d_in[1];
    const float* ea      = (const float*)d_in[2];
    const float* W1      = (const float*)d_in[3];
    const float* root1   = (const float*)d_in[4];
    const float* bias1   = (const float*)d_in[5];
    const float* W2      = (const float*)d_in[6];
    const float* root2   = (const float*)d_in[7];
    const float* bias2   = (const float*)d_in[8];
    float* out = (float*)d_out;

    const int N = in_sizes[0] / F_IN;      // 50000
    const int E = in_sizes[2];             // 1600000
    const int NB = (N + 255) >> BKT_SH;    // 196

    char* base = (char*)d_ws;
    size_t off = 0;
    auto alloc = [&](size_t bytes) {
        char* p = base + off;
        off = (off + bytes + 255) & ~(size_t)255;
        return (void*)p;
    };
    unsigned short* xwk1 = (unsigned short*)alloc((size_t)N * KS * HID * 2); // 12.8 MB
    float* xr1           = (float*)alloc((size_t)N * HID * 4);               // 6.4 MB
    float* h             = (float*)alloc((size_t)N * HID * 4);               // 6.4 MB
    int* offs            = (int*)alloc(((size_t)N + 1) * 4);
    int* bcnt            = (int*)alloc((size_t)NB * 4);
    int* bbase           = (int*)alloc(((size_t)NB + 1) * 4);
    int* gcur            = (int*)alloc((size_t)NB * 4);
    unsigned* spk        = (unsigned*)alloc((size_t)E * 4);                  // 6.4 MB
    uint2* tpd           = (uint2*)alloc((size_t)E * 8);                     // 12.8 MB (own buffer:
                                          // xw1 writes xwk1 concurrently with node_sort reading tpd)
    unsigned short* xwk2 = xwk1;          // xw2 runs after agg1 -> safe
    float* xr2           = xr1;
    if (ws_size < off) return;

    int ebk = (E + TILE - 1) / TILE;
    int xb  = (N + 47) / 48;               // xw1 blocks (48 nodes each) = 1042

    hipMemsetAsync(bcnt, 0, (size_t)NB * 4, stream);
    bucket_hist_kernel<<<ebk, 256, 0, stream>>>(ei, bcnt, E, NB);
    mini_scan_kernel<<<1, 256, 0, stream>>>(bcnt, bbase, gcur, NB);
    bucket_scatter_kernel<<<ebk, 256, 0, stream>>>(ei, ea, gcur, tpd, E, NB);
    nsort_xw1_kernel<<<NB + xb, 256, 0, stream>>>(tpd, bbase, spk, offs, N, NB,
                                                  x, W1, root1, xwk1, xr1);
    agg1_kernel<<<(N + 3) / 4, 256, 0, stream>>>(xwk1, xr1, offs, spk, bias1, h, N);
    {
        int total = (N / 2) * 25;
        xw2_kernel<<<(total + 255) / 256, 256, 0, stream>>>(h, W2, root2, xwk2, xr2, N);
    }
    agg2_kernel<<<(N + 3) / 4, 256, 0, stream>>>(xwk2, xr2, offs, spk, bias2, out, N);
}